// Round 5
// baseline (449.204 us; speedup 1.0000x reference)
//
#include <hip/hip_runtime.h>
#include <math.h>

#define NNODES 8192
#define NEDGES 262144
#define FIN 512
#define FHID 512
#define FLAT 128

typedef unsigned short bfu;   // raw bf16 bits
typedef __attribute__((ext_vector_type(8))) short short8;
typedef __attribute__((ext_vector_type(4))) float f32x4;
typedef __attribute__((ext_vector_type(2))) float f32x2;
typedef __attribute__((ext_vector_type(4))) unsigned short us4;

__device__ __forceinline__ float bf2f(unsigned short u) {
    union { unsigned int i; float f; } c; c.i = ((unsigned int)u) << 16; return c.f;
}
__device__ __forceinline__ unsigned short f2bf(float f) {
    union { float f; unsigned int i; } c; c.f = f;
    unsigned int i = c.i;
    unsigned int r = (i + 0x7FFFu + ((i >> 16) & 1u)) >> 16;  // RNE
    return (unsigned short)r;
}

// accumulate 4 bf16 features (one uint2) with weight w
__device__ __forceinline__ void acc4(float* acc, uint2 v, float w) {
    acc[0] += w * bf2f((unsigned short)(v.x & 0xFFFF));
    acc[1] += w * bf2f((unsigned short)(v.x >> 16));
    acc[2] += w * bf2f((unsigned short)(v.y & 0xFFFF));
    acc[3] += w * bf2f((unsigned short)(v.y >> 16));
}

// ---------- graph preprocessing ----------
__global__ void k_zero(int* p, int n) {
    int i = blockIdx.x * blockDim.x + threadIdx.x;
    if (i < n) p[i] = 0;
}

__global__ void k_count(const int* __restrict__ ei, int* __restrict__ deg) {
    int e = blockIdx.x * blockDim.x + threadIdx.x;
    if (e < NEDGES) atomicAdd(&deg[ei[NEDGES + e]], 1);
}

// single block, 256 threads: exclusive scan of deg -> row_start, plus dinv = rsqrt(deg+1)
__global__ void k_scan(const int* __restrict__ deg, int* __restrict__ row_start,
                       float* __restrict__ dinv) {
    __shared__ int part[256];
    int t = threadIdx.x, base = t * 32;
    int s = 0;
    for (int i = 0; i < 32; i++) s += deg[base + i];
    part[t] = s;
    __syncthreads();
    for (int off = 1; off < 256; off <<= 1) {
        int v = (t >= off) ? part[t - off] : 0;
        __syncthreads();
        part[t] += v;
        __syncthreads();
    }
    int run = (t == 0) ? 0 : part[t - 1];
    for (int i = 0; i < 32; i++) {
        int d = deg[base + i];
        row_start[base + i] = run;
        run += d;
        dinv[base + i] = rsqrtf((float)(d + 1));  // +1 self-loop
    }
    if (t == 255) row_start[NNODES] = run;
}

// ---------- fused: edge scatter (packed {src,w} pairs) + weight transposes + x->bf16 ----------
// blocks [0,1024): scatter; [1024,1280): Bt1 tiles; [1280,1408): Bt2 tiles; [1408,5504): cvt x
__global__ void k_scatter_prep(const int* __restrict__ ei, const int* __restrict__ row_start,
                               int* __restrict__ cursor, int2* __restrict__ ep,
                               const float* __restrict__ dinv,
                               const float* __restrict__ W1, const float* __restrict__ Wmu,
                               const float* __restrict__ Wlv, const float* __restrict__ x,
                               bfu* __restrict__ Bt1, bfu* __restrict__ Bt2,
                               bfu* __restrict__ xb) {
    __shared__ bfu tile[32][33];   // +1 pad breaks bank aliasing
    int b = blockIdx.x;
    if (b < 1024) {
        int e = b * 256 + threadIdx.x;
        int src = ei[e];
        int dst = ei[NEDGES + e];
        int p = atomicAdd(&cursor[dst], 1);
        int2 pr;
        pr.x = src;
        pr.y = __float_as_int(dinv[src]);
        ep[row_start[dst] + p] = pr;
    } else if (b < 1280) {
        int bb = b - 1024;
        int tx = threadIdx.x & 31, ty = threadIdx.x >> 5;   // 32 x 8
        int nb = bb & 15, kb = bb >> 4;
        int n0 = nb * 32, k0 = kb * 32;
#pragma unroll
        for (int i = 0; i < 32; i += 8)
            tile[ty + i][tx] = f2bf(W1[(size_t)(k0 + ty + i) * 512 + n0 + tx]);
        __syncthreads();
#pragma unroll
        for (int i = 0; i < 32; i += 8)
            Bt1[(size_t)(n0 + ty + i) * 512 + k0 + tx] = tile[tx][ty + i];
    } else if (b < 1408) {
        int bb = b - 1280;
        int tx = threadIdx.x & 31, ty = threadIdx.x >> 5;
        int nb = bb & 7, kb = bb >> 3;
        int n0 = nb * 32, k0 = kb * 32;
        const float* Wsel = (n0 < 128) ? Wmu : Wlv;
        int noff = (n0 < 128) ? 0 : 128;
#pragma unroll
        for (int i = 0; i < 32; i += 8)
            tile[ty + i][tx] = f2bf(Wsel[(size_t)(k0 + ty + i) * 128 + (n0 + tx - noff)]);
        __syncthreads();
#pragma unroll
        for (int i = 0; i < 32; i += 8)
            Bt2[(size_t)(n0 + ty + i) * 512 + k0 + tx] = tile[tx][ty + i];
    } else {
        int i = (b - 1408) * 256 + threadIdx.x;  // over float4s
        const float4 v = ((const float4*)x)[i];
        ushort2 lo = {f2bf(v.x), f2bf(v.y)};
        ushort2 hi = {f2bf(v.z), f2bf(v.w)};
        ((ushort2*)xb)[2 * i] = lo;
        ((ushort2*)xb)[2 * i + 1] = hi;
    }
}

// ---------- generic NT GEMM: C[M,N] = A[M,K] @ Bt[N,K]^T, bf16 in/out, fp32 acc ----------
// K compile-time -> k-loop unrolls x2 for load/MFMA pipelining.
template <int TM, int TN, int K>
__global__ void k_gemm_nt(const bfu* __restrict__ A, const bfu* __restrict__ Bt,
                          bfu* __restrict__ C, int M, int N) {
    int wid  = (blockIdx.x * blockDim.x + threadIdx.x) >> 6;
    int lane = threadIdx.x & 63;
    int l = lane & 15, q = lane >> 4;
    int tn = N / (16 * TN);
    int m0 = (wid / tn) * (16 * TM), n0 = (wid % tn) * (16 * TN);

    f32x4 acc[TM][TN];
#pragma unroll
    for (int a = 0; a < TM; a++)
#pragma unroll
        for (int b = 0; b < TN; b++) acc[a][b] = (f32x4){0.f, 0.f, 0.f, 0.f};

    const bfu* Ap = A + (size_t)(m0 + l) * K + q * 8;
    const bfu* Bp = Bt + (size_t)(n0 + l) * K + q * 8;

#pragma unroll 2
    for (int k0 = 0; k0 < K; k0 += 32) {
        short8 av[TM], bv[TN];
#pragma unroll
        for (int mi = 0; mi < TM; mi++)
            av[mi] = *(const short8*)(Ap + (size_t)mi * 16 * K + k0);
#pragma unroll
        for (int ni = 0; ni < TN; ni++)
            bv[ni] = *(const short8*)(Bp + (size_t)ni * 16 * K + k0);
#pragma unroll
        for (int mi = 0; mi < TM; mi++)
#pragma unroll
            for (int ni = 0; ni < TN; ni++)
                acc[mi][ni] = __builtin_amdgcn_mfma_f32_16x16x32_bf16(bv[ni], av[mi],
                                                                     acc[mi][ni], 0, 0, 0);
    }

    // acc[mi][ni][r] = C[m0+mi*16+l][n0+ni*16+q*4+r]
#pragma unroll
    for (int mi = 0; mi < TM; mi++) {
        int row = m0 + mi * 16 + l;
#pragma unroll
        for (int ni = 0; ni < TN; ni++) {
            int col = n0 + ni * 16 + q * 4;
            f32x4 v = acc[mi][ni];
            us4 o = {f2bf(v[0]), f2bf(v[1]), f2bf(v[2]), f2bf(v[3])};
            *(us4*)(C + (size_t)row * N + col) = o;
        }
    }
}

// ---------- symmetric decode: A_pred = sigmoid(z @ z^T), upper-triangle tiles only ----------
__global__ __launch_bounds__(256) void k_decode_sym(const bfu* __restrict__ Z,
                                                    float* __restrict__ C) {
    __shared__ float ldsT[4][2][16][68];
    int wid  = (blockIdx.x * blockDim.x + threadIdx.x) >> 6;
    int wv   = threadIdx.x >> 6;
    int lane = threadIdx.x & 63;
    int l = lane & 15, q = lane >> 4;

    // triangular map: wid in [0, 8256) -> (ti, tj), ti <= tj < 128; off(t) = t*(257-t)/2
    int idx = wid;
    int ti = (int)((257.0 - sqrt(66049.0 - 8.0 * (double)idx)) * 0.5);
    if (ti > 127) ti = 127;
    if (ti < 0) ti = 0;
    while (ti > 0 && (ti * (257 - ti)) / 2 > idx) ti--;
    while (ti < 127 && ((ti + 1) * (256 - ti)) / 2 <= idx) ti++;
    int tj = ti + (idx - (ti * (257 - ti)) / 2);
    int m0 = ti * 64, n0 = tj * 64;

    f32x4 acc[4][4];
#pragma unroll
    for (int a = 0; a < 4; a++)
#pragma unroll
        for (int b = 0; b < 4; b++) acc[a][b] = (f32x4){0.f, 0.f, 0.f, 0.f};

    const bfu* Ap = Z + (size_t)(m0 + l) * 128 + q * 8;
    const bfu* Bp = Z + (size_t)(n0 + l) * 128 + q * 8;

#pragma unroll
    for (int k0 = 0; k0 < 128; k0 += 32) {
        short8 av[4], bv[4];
#pragma unroll
        for (int mi = 0; mi < 4; mi++)
            av[mi] = *(const short8*)(Ap + (size_t)mi * 16 * 128 + k0);
#pragma unroll
        for (int ni = 0; ni < 4; ni++)
            bv[ni] = *(const short8*)(Bp + (size_t)ni * 16 * 128 + k0);
#pragma unroll
        for (int mi = 0; mi < 4; mi++)
#pragma unroll
            for (int ni = 0; ni < 4; ni++)
                acc[mi][ni] = __builtin_amdgcn_mfma_f32_16x16x32_bf16(bv[ni], av[mi],
                                                                     acc[mi][ni], 0, 0, 0);
    }

    // sigmoid in place (identical op sequence -> bit-identical)
#pragma unroll
    for (int mi = 0; mi < 4; mi++)
#pragma unroll
        for (int ni = 0; ni < 4; ni++)
#pragma unroll
            for (int r = 0; r < 4; r++)
                acc[mi][ni][r] = __builtin_amdgcn_rcpf(1.0f + __expf(-acc[mi][ni][r]));

    // upper tile: coalesced f32x4 nt-stores
#pragma unroll
    for (int mi = 0; mi < 4; mi++) {
        int row = m0 + mi * 16 + l;
#pragma unroll
        for (int ni = 0; ni < 4; ni++) {
            int col = n0 + ni * 16 + q * 4;
            __builtin_nontemporal_store(acc[mi][ni], (f32x4*)(C + (size_t)row * 8192 + col));
        }
    }

    // mirror (lower) tile via LDS chunk-transpose; f32x4-wide stores
    if (ti != tj) {
#pragma unroll
        for (int ni = 0; ni < 4; ni++) {
            int p = ni & 1;
#pragma unroll
            for (int mi = 0; mi < 4; mi++)
#pragma unroll
                for (int r = 0; r < 4; r++)
                    ldsT[wv][p][q * 4 + r][mi * 16 + l] = acc[mi][ni][r];
            asm volatile("s_waitcnt lgkmcnt(0)" ::: "memory");
#pragma unroll
            for (int jj = 0; jj < 4; jj++) {
                f32x4 v = *(const f32x4*)&ldsT[wv][p][jj * 4 + q][l * 4];
                __builtin_nontemporal_store(
                    v, (f32x4*)(C + (size_t)(n0 + ni * 16 + jj * 4 + q) * 8192 + m0 + l * 4));
            }
        }
    }
}

// ---------- aggregation ----------
// layer 1, TWO FEATURE PASSES: per pass the gathered working set is a 4 MB slice of h0
// (8192 nodes x 256 feats x bf16) = one XCD L2. Chunk-major grid phases the passes so
// each XCD L2 holds one slice. Per-feature accumulation order unchanged -> bit-identical.
// hout stored non-temporally so the write stream doesn't evict the h0 slice.
__global__ void k_agg1(const bfu* __restrict__ hin, const int2* __restrict__ ep,
                       const int* __restrict__ rs, const float* __restrict__ dinv,
                       const float* __restrict__ bias, bfu* __restrict__ hout) {
    int bid = blockIdx.x;
    int chunk = bid >> 11;                          // 0 or 1: feature half
    int node = (bid & 2047) * 4 + (threadIdx.x >> 6);
    int lane = threadIdx.x & 63;
    int f = chunk * 256 + lane * 4;                 // 4 features per lane (8B gathers)
    int s = rs[node], e = rs[node + 1];
    float di = dinv[node];
    float acc[4];
#pragma unroll
    for (int k = 0; k < 4; k++) acc[k] = 0.f;
    const bfu* hf = hin + f;

    int ed = s;
    for (; ed + 4 <= e; ed += 4) {
        int2 p0 = ep[ed], p1 = ep[ed + 1], p2 = ep[ed + 2], p3 = ep[ed + 3];
        uint2 v0 = *(const uint2*)(hf + (size_t)p0.x * FHID);
        uint2 v1 = *(const uint2*)(hf + (size_t)p1.x * FHID);
        uint2 v2 = *(const uint2*)(hf + (size_t)p2.x * FHID);
        uint2 v3 = *(const uint2*)(hf + (size_t)p3.x * FHID);
        acc4(acc, v0, __int_as_float(p0.y));
        acc4(acc, v1, __int_as_float(p1.y));
        acc4(acc, v2, __int_as_float(p2.y));
        acc4(acc, v3, __int_as_float(p3.y));
    }
    for (; ed < e; ed++) {
        int2 p0 = ep[ed];
        uint2 v0 = *(const uint2*)(hf + (size_t)p0.x * FHID);
        acc4(acc, v0, __int_as_float(p0.y));
    }
    {   // self-loop
        uint2 vs = *(const uint2*)(hf + (size_t)node * FHID);
        acc4(acc, vs, di);
    }

    f32x4 b = *(const f32x4*)(bias + f);
    float o[4];
#pragma unroll
    for (int k = 0; k < 4; k++) o[k] = fmaxf(di * acc[k] + b[k], 0.f);
    unsigned long long ow =
        (unsigned long long)((unsigned int)f2bf(o[0]) | ((unsigned int)f2bf(o[1]) << 16)) |
        ((unsigned long long)((unsigned int)f2bf(o[2]) | ((unsigned int)f2bf(o[3]) << 16)) << 32);
    __builtin_nontemporal_store(ow, (unsigned long long*)(hout + (size_t)node * FHID + f));
}

// layers 2/3 fused: F=256 ([mu | logvar]) -> lane covers 4 features (8B gathers);
// working set (4 MB) already L2-sized -> single pass.
__global__ void k_agg2(const bfu* __restrict__ hin, const int2* __restrict__ ep,
                       const int* __restrict__ rs, const float* __restrict__ dinv,
                       const float* __restrict__ bmu, const float* __restrict__ blv,
                       float* __restrict__ out_mu, float* __restrict__ out_lv,
                       float* __restrict__ out_z, bfu* __restrict__ ws_z) {
    int node = blockIdx.x * 4 + (threadIdx.x >> 6);
    int lane = threadIdx.x & 63;
    int f = lane * 4;
    int s = rs[node], e = rs[node + 1];
    float di = dinv[node];
    float acc[4];
#pragma unroll
    for (int k = 0; k < 4; k++) acc[k] = 0.f;
    const bfu* hf = hin + f;

    int ed = s;
    for (; ed + 2 <= e; ed += 2) {
        int2 p0 = ep[ed], p1 = ep[ed + 1];
        uint2 v0 = *(const uint2*)(hf + (size_t)p0.x * 256);
        uint2 v1 = *(const uint2*)(hf + (size_t)p1.x * 256);
        acc4(acc, v0, __int_as_float(p0.y));
        acc4(acc, v1, __int_as_float(p1.y));
    }
    if (ed < e) {
        int2 p0 = ep[ed];
        uint2 v0 = *(const uint2*)(hf + (size_t)p0.x * 256);
        acc4(acc, v0, __int_as_float(p0.y));
    }
    {   // self-loop
        uint2 vs = *(const uint2*)(hf + (size_t)node * 256);
        acc4(acc, vs, di);
    }

    if (f < 128) {
        f32x4 bm = *(const f32x4*)(bmu + f);
        f32x4 fv;
#pragma unroll
        for (int k = 0; k < 4; k++) fv[k] = di * acc[k] + bm[k];
        __builtin_nontemporal_store(fv, (f32x4*)(out_mu + (size_t)node * FLAT + f));
        __builtin_nontemporal_store(fv, (f32x4*)(out_z + (size_t)node * FLAT + f));  // z = mu
        unsigned long long bw =
            (unsigned long long)((unsigned int)f2bf(fv[0]) | ((unsigned int)f2bf(fv[1]) << 16)) |
            ((unsigned long long)((unsigned int)f2bf(fv[2]) | ((unsigned int)f2bf(fv[3]) << 16)) << 32);
        *(unsigned long long*)(ws_z + (size_t)node * FLAT + f) = bw;  // reused by decode: keep cached
    } else {
        int fl = f - 128;
        f32x4 bl = *(const f32x4*)(blv + fl);
        f32x4 fv;
#pragma unroll
        for (int k = 0; k < 4; k++) fv[k] = di * acc[k] + bl[k];
        __builtin_nontemporal_store(fv, (f32x4*)(out_lv + (size_t)node * FLAT + fl));
    }
}

extern "C" void kernel_launch(void* const* d_in, const int* in_sizes, int n_in,
                              void* d_out, int out_size, void* d_ws, size_t ws_size,
                              hipStream_t stream) {
    const int*   ei  = (const int*)d_in[0];
    const float* x   = (const float*)d_in[1];
    const float* W1  = (const float*)d_in[2];
    const float* b1  = (const float*)d_in[3];
    const float* Wmu = (const float*)d_in[4];
    const float* bmu = (const float*)d_in[5];
    const float* Wlv = (const float*)d_in[6];
    const float* blv = (const float*)d_in[7];
    float* out = (float*)d_out;

    char* wsb = (char*)d_ws;
    size_t off = 0;
    auto alloc = [&](size_t bytes) -> char* {
        char* p = wsb + off;
        off += (bytes + 255) & ~(size_t)255;
        return p;
    };
    int*   deg       = (int*)alloc(NNODES * 4);
    int*   cursor    = (int*)alloc(NNODES * 4);   // contiguous after deg
    int*   row_start = (int*)alloc((NNODES + 1) * 4);
    float* dinv      = (float*)alloc(NNODES * 4);
    int2*  ep        = (int2*)alloc((size_t)NEDGES * 8);
    bfu*   Bt1       = (bfu*)alloc(512 * 512 * 2);
    bfu*   Bt2       = (bfu*)alloc(256 * 512 * 2);
    bfu*   xb        = (bfu*)alloc((size_t)NNODES * FIN * 2);
    bfu*   h0        = (bfu*)alloc((size_t)NNODES * FHID * 2);
    bfu*   h         = (bfu*)alloc((size_t)NNODES * FHID * 2);
    bfu*   hml       = (bfu*)alloc((size_t)NNODES * 256 * 2);
    bfu*   zb        = (bfu*)alloc((size_t)NNODES * FLAT * 2);

    float* out_mu = out + (size_t)NNODES * NNODES;
    float* out_lv = out_mu + (size_t)NNODES * FLAT;
    float* out_z  = out_lv + (size_t)NNODES * FLAT;

    // graph prep
    k_zero<<<(2 * NNODES + 255) / 256, 256, 0, stream>>>(deg, 2 * NNODES);  // deg + cursor
    k_count<<<NEDGES / 256, 256, 0, stream>>>(ei, deg);
    k_scan<<<1, 256, 0, stream>>>(deg, row_start, dinv);
    k_scatter_prep<<<1024 + 256 + 128 + 4096, 256, 0, stream>>>(
        ei, row_start, cursor, ep, dinv, W1, Wmu, Wlv, x, Bt1, Bt2, xb);

    // layer 1: h0 = x @ W1 ; h = relu(agg(h0) + b1)
    k_gemm_nt<4, 2, 512><<<(8192 / 64) * (512 / 32) / 4, 256, 0, stream>>>(
        xb, Bt1, h0, 8192, 512);
    k_agg1<<<2 * (NNODES / 4), 256, 0, stream>>>(h0, ep, row_start, dinv, b1, h);

    // layers 2+3 fused: hml = h @ [Wmu|Wlv]
    k_gemm_nt<2, 2, 512><<<(8192 / 32) * (256 / 32) / 4, 256, 0, stream>>>(
        h, Bt2, hml, 8192, 256);
    k_agg2<<<NNODES / 4, 256, 0, stream>>>(hml, ep, row_start, dinv, bmu, blv,
                                           out_mu, out_lv, out_z, zb);

    // decode: upper-triangle tile-pairs only (8256 wave-tiles / 4 waves per block)
    k_decode_sym<<<8256 / 4, 256, 0, stream>>>(zb, out);
}